// Round 16
// baseline (682.462 us; speedup 1.0000x reference)
//
#include <hip/hip_runtime.h>
#include <hip/hip_cooperative_groups.h>

namespace cg = cooperative_groups;

// ---------------------------------------------------------------------------
// Res_up block, round 16: cooperative mega-kernel v2. GRID=512 with
// __launch_bounds__(256,2) -> 2x co-residency margin (round 15's 1024-at-max
// launch was rejected by the runtime and never ran).
// Phases: prep | scatter | gemmA(512) | knn(512) | agg1(256)||pfA(256) |
// nodeD(64) | pfE | aggBoth | nodeF(512) | bn.
// Sizes fixed: Nc=4096, Nf=16384, Ec=65536, Ef=262144, Cin=128, Ch=64, Co=128.
// ---------------------------------------------------------------------------

#define SELU_SCALE 1.0507009873554805f
#define SELU_ALPHA 1.6732632423543772f

static constexpr int NC = 4096, NF = 16384, EC = 65536, EF = 262144;
static constexpr int G = 32, NCELL = G * G;
static constexpr int CAPF = 64, CAPC = 64, CAPG = 32;
static constexpr int GRID = 512;

typedef __attribute__((ext_vector_type(8))) short short8v;
typedef __attribute__((ext_vector_type(4))) float f32x4;
typedef unsigned short ushort_t;
typedef unsigned long long u64;

__device__ __forceinline__ float selu_f(float x) {
    return x > 0.0f ? SELU_SCALE * x
                    : SELU_SCALE * SELU_ALPHA * (__expf(x) - 1.0f);
}
__device__ __forceinline__ ushort_t f2bf(float f) {
    unsigned u = __float_as_uint(f);
    u += 0x7FFFu + ((u >> 16) & 1u);
    return (ushort_t)(u >> 16);
}
__device__ __forceinline__ float bf2f(ushort_t u) {
    return __uint_as_float(((unsigned)u) << 16);
}
__device__ __forceinline__ int cell_of(float2 p) {
    int cx = (int)(p.x * (float)G); cx = cx > G - 1 ? G - 1 : cx;
    int cy = (int)(p.y * (float)G); cy = cy > G - 1 ? G - 1 : cy;
    return cy * G + cx;
}
__device__ __forceinline__ void ins3(u64& a0, u64& a1, u64& a2, u64 v) {
    if (v < a2) {
        if (v < a1) {
            a2 = a1;
            if (v < a0) { a1 = a0; a0 = v; } else a1 = v;
        } else a2 = v;
    }
}

template <int K, typename F>
__device__ __forceinline__ void wfrag(F getw, ushort_t* __restrict__ dst, int idx) {
    constexpr int KC = K / 32;
    const int f = idx >> 9;
    const int r = idx & 511;
    const int lane = r >> 3;
    const int e = r & 7;
    const int ntile = f / KC;
    const int kc = f - ntile * KC;
    const int k = kc * 32 + ((lane >> 4) << 3) + e;
    const int col = ntile * 16 + (lane & 15);
    dst[idx] = f2bf(getw(k, col));
}

struct KParams {
    const float* x; const float* pos_c; const float* pos_f;
    const int* ei_f; const int* ei_c;
    const float* We1; const float* be1; const float* Wn1; const float* bn1;
    const float* We2; const float* be2; const float* Wn2; const float* bn2;
    const float* WeS; const float* beS; const float* WnS; const float* bnS;
    const float* gamma; const float* beta;
    ushort_t* xb; ushort_t* WfA; ushort_t* WfE; ushort_t* WfSn;
    ushort_t* Wf1n; ushort_t* Wf2n;
    int* cntF; int* srtF; int* cntC; int* srtC; int* cntG;
    float4* grecs; float4* meta;
    ushort_t* RA; ushort_t* RE; ushort_t* PF; ushort_t* QF;
    ushort_t* UfS; ushort_t* Uf2; ushort_t* aggS; ushort_t* agg2;
    ushort_t* agg1b;
    float* stats; float* outp;
};

static constexpr int PREP_TOTAL = NC * 128 + 65536 + 24576 + 16384 + 12288
                                + 16384 + NF + NC + NCELL + 256;
static constexpr int SORT_ITEMS = EF + EC + NC;

__global__ __launch_bounds__(256, 2) void mega_kernel(KParams P) {
    const int tid = threadIdx.x;
    const int bid = blockIdx.x;
    const int wid = tid >> 6, lane = tid & 63;
    cg::grid_group gg = cg::this_grid();
    __shared__ ushort_t h1s[64][72];
    __shared__ float s_red[256];

    // ===== P1: prep (x->bf16, weight frags, zero counters/stats) =====
    for (int it = bid * 256 + tid; it < PREP_TOTAL; it += GRID * 256) {
        int i = it;
        if (i < NC * 128) { P.xb[i] = f2bf(P.x[i]); continue; }
        i -= NC * 128;
        if (i < 65536) {
            const float* WeS = P.WeS; const float* WnS = P.WnS;
            const float* We1 = P.We1;
            wfrag<128>([&](int k, int j) {
                return j < 128 ? WeS[k * 128 + j]
                     : j < 256 ? WeS[(128 + k) * 128 + (j - 128)]
                     : j < 384 ? WnS[k * 128 + (j - 256)]
                     : j < 448 ? We1[k * 64 + (j - 384)]
                               : We1[(128 + k) * 64 + (j - 448)];
            }, P.WfA, i);
            continue;
        }
        i -= 65536;
        if (i < 24576) {
            const float* We2 = P.We2; const float* Wn2 = P.Wn2;
            wfrag<64>([&](int k, int j) {
                return j < 128 ? We2[k * 128 + j]
                     : j < 256 ? We2[(64 + k) * 128 + (j - 128)]
                               : Wn2[k * 128 + (j - 256)];
            }, P.WfE, i);
            continue;
        }
        i -= 24576;
        if (i < 16384) {
            const float* WnS = P.WnS;
            wfrag<128>([&](int k, int j) { return WnS[(128 + k) * 128 + j]; },
                       P.WfSn, i);
            continue;
        }
        i -= 16384;
        if (i < 12288) {
            const float* Wn1 = P.Wn1;
            wfrag<192>([&](int k, int j) { return Wn1[k * 64 + j]; }, P.Wf1n, i);
            continue;
        }
        i -= 12288;
        if (i < 16384) {
            const float* Wn2 = P.Wn2;
            wfrag<128>([&](int k, int j) { return Wn2[(64 + k) * 128 + j]; },
                       P.Wf2n, i);
            continue;
        }
        i -= 16384;
        if (i < NF) { P.cntF[i] = 0; continue; }
        i -= NF;
        if (i < NC) { P.cntC[i] = 0; continue; }
        i -= NC;
        if (i < NCELL) { P.cntG[i] = 0; continue; }
        i -= NCELL;
        P.stats[i] = 0.0f;
    }
    gg.sync();

    // ===== P2: direct scatter into fixed-stride buckets =====
    for (int it = bid * 256 + tid; it < SORT_ITEMS; it += GRID * 256) {
        int i = it;
        if (i < EF) {
            const int dst = P.ei_f[EF + i];
            const int slot = atomicAdd(&P.cntF[dst], 1);
            P.srtF[dst * CAPF + slot] = P.ei_f[i];
            continue;
        }
        i -= EF;
        if (i < EC) {
            const int dst = P.ei_c[EC + i];
            const int slot = atomicAdd(&P.cntC[dst], 1);
            P.srtC[dst * CAPC + slot] = P.ei_c[i];
            continue;
        }
        i -= EC;
        const float2 p = ((const float2*)P.pos_c)[i];
        const int c = cell_of(p);
        const int slot = atomicAdd(&P.cntG[c], 1);
        float4 rec;
        rec.x = p.x; rec.y = p.y; rec.z = __int_as_float(i); rec.w = 0.0f;
        P.grecs[c * CAPG + slot] = rec;
    }
    gg.sync();

    // ===== P3: RA GEMM (512 blocks, 4 n-tiles each) =====
    {
        const int bx = bid >> 3, by = bid & 7;
        const int row_base = bx * 64 + wid * 16;
        const int row_a = row_base + (lane & 15);
        const int klane = (lane >> 4) << 3;
        short8v a[4];
#pragma unroll
        for (int f = 0; f < 4; ++f)
            a[f] = *(const short8v*)(P.xb + (size_t)row_a * 128 + f * 32 + klane);
#pragma unroll
        for (int q = 0; q < 4; ++q) {
            const int ntg = by * 4 + q;
            f32x4 acc = {0.0f, 0.0f, 0.0f, 0.0f};
#pragma unroll
            for (int f = 0; f < 4; ++f) {
                const short8v b =
                    *(const short8v*)(P.WfA + (size_t)(ntg * 4 + f) * 512 + lane * 8);
                acc = __builtin_amdgcn_mfma_f32_16x16x32_bf16(a[f], b, acc, 0, 0, 0);
            }
            const int col = ntg * 16 + (lane & 15);
            const int r0 = row_base + ((lane >> 4) << 2);
#pragma unroll
            for (int r = 0; r < 4; ++r)
                P.RA[(size_t)(r0 + r) * 512 + col] = f2bf(acc[r]);
        }
    }
    gg.sync();

    // ===== P4: knn (all 512 blocks, 8 lanes per fine point) =====
    {
        const int g8 = bid * 256 + tid;          // 131072 = 8*NF
        const int t = g8 >> 3;
        const int sub = g8 & 7;
        const float2 p = ((const float2*)P.pos_f)[t];
        int cx = (int)(p.x * (float)G); cx = cx > G - 1 ? G - 1 : cx;
        int cy = (int)(p.y * (float)G); cy = cy > G - 1 ? G - 1 : cy;
        const float h = 1.0f / (float)G;
        u64 b0 = ~0ull, b1 = ~0ull, b2 = ~0ull;

        {
            const int xx0 = cx - 1 < 0 ? 0 : cx - 1;
            const int xx1 = cx + 1 > G - 1 ? G - 1 : cx + 1;
            const int yy0 = cy - 1 < 0 ? 0 : cy - 1;
            const int yy1 = cy + 1 > G - 1 ? G - 1 : cy + 1;
            for (int yy = yy0; yy <= yy1; ++yy)
                for (int xx = xx0; xx <= xx1; ++xx) {
                    const int c = yy * G + xx;
                    const int cn = P.cntG[c];
                    for (int i = sub; i < cn; i += 8) {
                        const float4 q = P.grecs[(c << 5) + i];
                        const float dx = p.x - q.x;
                        const float dy = p.y - q.y;
                        const float d = dx * dx + dy * dy;
                        ins3(b0, b1, b2, ((u64)__float_as_uint(d) << 32) |
                                         (u64)__float_as_uint(q.z));
                    }
                }
#pragma unroll
            for (int mk = 1; mk <= 4; mk <<= 1) {
                const u64 e0 = __shfl_xor(b0, mk);
                const u64 e1 = __shfl_xor(b1, mk);
                const u64 e2 = __shfl_xor(b2, mk);
                ins3(b0, b1, b2, e0);
                ins3(b0, b1, b2, e1);
                ins3(b0, b1, b2, e2);
            }
        }

        for (int r = 2; r < G; ++r) {
            const float bd = __uint_as_float((unsigned)(b2 >> 32));
            const float lim = (float)(r - 1) * h;
            if (bd < lim * lim) break;   // NaN-safe: continues while unfilled
            u64 c0 = ~0ull, c1 = ~0ull, c2 = ~0ull;
            auto scan_full = [&](int c) {
                const int cn = P.cntG[c];
                for (int i = 0; i < cn; ++i) {
                    const float4 q = P.grecs[(c << 5) + i];
                    const float dx = p.x - q.x;
                    const float dy = p.y - q.y;
                    const float d = dx * dx + dy * dy;
                    ins3(c0, c1, c2, ((u64)__float_as_uint(d) << 32) |
                                     (u64)__float_as_uint(q.z));
                }
            };
            const int side = sub & 3, phase = sub >> 2;
            const int x0 = cx - r < 0 ? 0 : cx - r;
            const int x1 = cx + r > G - 1 ? G - 1 : cx + r;
            const int yi0 = cy - r + 1 < 0 ? 0 : cy - r + 1;
            const int yi1 = cy + r - 1 > G - 1 ? G - 1 : cy + r - 1;
            if (side == 0) {
                if (cy - r >= 0)
                    for (int xx = x0 + phase; xx <= x1; xx += 2)
                        scan_full((cy - r) * G + xx);
            } else if (side == 1) {
                if (cy + r <= G - 1)
                    for (int xx = x0 + phase; xx <= x1; xx += 2)
                        scan_full((cy + r) * G + xx);
            } else if (side == 2) {
                if (cx - r >= 0)
                    for (int yy = yi0 + phase; yy <= yi1; yy += 2)
                        scan_full(yy * G + cx - r);
            } else {
                if (cx + r <= G - 1)
                    for (int yy = yi0 + phase; yy <= yi1; yy += 2)
                        scan_full(yy * G + cx + r);
            }
#pragma unroll
            for (int mk = 1; mk <= 4; mk <<= 1) {
                const u64 e0 = __shfl_xor(c0, mk);
                const u64 e1 = __shfl_xor(c1, mk);
                const u64 e2 = __shfl_xor(c2, mk);
                ins3(c0, c1, c2, e0);
                ins3(c0, c1, c2, e1);
                ins3(c0, c1, c2, e2);
            }
            ins3(b0, b1, b2, c0);
            ins3(b0, b1, b2, c1);
            ins3(b0, b1, b2, c2);
        }

        if (sub == 0) {
            const float d0 = __uint_as_float((unsigned)(b0 >> 32));
            const float d1 = __uint_as_float((unsigned)(b1 >> 32));
            const float d2 = __uint_as_float((unsigned)(b2 >> 32));
            const float w0 = 1.0f / fmaxf(d0, 1e-16f);
            const float w1 = 1.0f / fmaxf(d1, 1e-16f);
            const float w2 = 1.0f / fmaxf(d2, 1e-16f);
            const float s = 1.0f / (w0 + w1 + w2);
            float4 mi;
            mi.x = __uint_as_float((unsigned)(b0 & 0xffffffffu));
            mi.y = __uint_as_float((unsigned)(b1 & 0xffffffffu));
            mi.z = __uint_as_float((unsigned)(b2 & 0xffffffffu));
            mi.w = 0.0f;
            float4 mw;
            mw.x = w0 * s; mw.y = w1 * s; mw.z = w2 * s; mw.w = 0.0f;
            P.meta[2 * t] = mi;
            P.meta[2 * t + 1] = mw;
        }
    }
    gg.sync();

    // ===== P5: agg1 (blocks 0..255) || pfA (blocks 256..511) =====
    if (bid < 256) {
        const int n0 = bid * 16 + wid * 4;
#pragma unroll
        for (int k = 0; k < 4; ++k) {
            const int n = n0 + k;
            const int b1 = P.cntC[n];
            const int* bucket = P.srtC + n * CAPC;
            const float q = bf2f(P.RA[(unsigned)n * 512u + 448 + lane]) + P.be1[lane];
            const unsigned clo = 384u + (unsigned)lane;
            float s = 0.0f;
            int e = 0;
            for (; e + 4 <= b1; e += 4) {
                const int s0 = bucket[e], s1 = bucket[e + 1];
                const int s2 = bucket[e + 2], s3 = bucket[e + 3];
                const ushort_t v0 = P.RA[(unsigned)s0 * 512u + clo];
                const ushort_t v1 = P.RA[(unsigned)s1 * 512u + clo];
                const ushort_t v2 = P.RA[(unsigned)s2 * 512u + clo];
                const ushort_t v3 = P.RA[(unsigned)s3 * 512u + clo];
                s += selu_f(bf2f(v0) + q);
                s += selu_f(bf2f(v1) + q);
                s += selu_f(bf2f(v2) + q);
                s += selu_f(bf2f(v3) + q);
            }
            for (; e < b1; ++e)
                s += selu_f(bf2f(P.RA[(unsigned)bucket[e] * 512u + clo]) + q);
            P.agg1b[(size_t)n * 64 + lane] = f2bf(s);
        }
    } else {
        // pfA: RA-side interpolation (PF.xy, QF.xy, UfS)
        const int w = (bid - 256) * 4 + wid;   // 0..1023
        const unsigned lo = (unsigned)(lane * 2);
        for (int n = w; n < NF; n += 1024) {
            const float4 mi = P.meta[2 * n];
            const float4 mw = P.meta[2 * n + 1];
            const unsigned a0 = __float_as_uint(mi.x) * 512 + lo;
            const unsigned a1 = __float_as_uint(mi.y) * 512 + lo;
            const unsigned a2 = __float_as_uint(mi.z) * 512 + lo;
            const ushort2 p0 = *(const ushort2*)(P.RA + a0);
            const ushort2 p1 = *(const ushort2*)(P.RA + a1);
            const ushort2 p2 = *(const ushort2*)(P.RA + a2);
            const ushort2 q0 = *(const ushort2*)(P.RA + a0 + 128);
            const ushort2 q1 = *(const ushort2*)(P.RA + a1 + 128);
            const ushort2 q2 = *(const ushort2*)(P.RA + a2 + 128);
            const ushort2 u0 = *(const ushort2*)(P.RA + a0 + 256);
            const ushort2 u1 = *(const ushort2*)(P.RA + a1 + 256);
            const ushort2 u2 = *(const ushort2*)(P.RA + a2 + 256);
            const float2 bS = *(const float2*)(P.beS + lane * 2);
            ushort2 o;
            o.x = f2bf(mw.x * bf2f(p0.x) + mw.y * bf2f(p1.x) + mw.z * bf2f(p2.x));
            o.y = f2bf(mw.x * bf2f(p0.y) + mw.y * bf2f(p1.y) + mw.z * bf2f(p2.y));
            *(ushort2*)(P.PF + (size_t)n * 256 + lane * 4) = o;
            o.x = f2bf(mw.x * bf2f(q0.x) + mw.y * bf2f(q1.x) + mw.z * bf2f(q2.x) + bS.x);
            o.y = f2bf(mw.x * bf2f(q0.y) + mw.y * bf2f(q1.y) + mw.z * bf2f(q2.y) + bS.y);
            *(ushort2*)(P.QF + (size_t)n * 256 + lane * 4) = o;
            o.x = f2bf(mw.x * bf2f(u0.x) + mw.y * bf2f(u1.x) + mw.z * bf2f(u2.x));
            o.y = f2bf(mw.x * bf2f(u0.y) + mw.y * bf2f(u1.y) + mw.z * bf2f(u2.y));
            *(ushort2*)(P.UfS + (size_t)n * 128 + lo) = o;
        }
    }
    gg.sync();

    // ===== P6: nodeD (blocks 0..63): h1 in LDS, then RE = h1 @ WfE =====
    if (bid < 64) {
        const int klane = (lane >> 4) << 3;
        const int row_base = bid * 64 + wid * 16;
        const int row_a = row_base + (lane & 15);
        short8v a[6];
#pragma unroll
        for (int f = 0; f < 4; ++f)
            a[f] = *(const short8v*)(P.xb + (size_t)row_a * 128 + f * 32 + klane);
#pragma unroll
        for (int f = 0; f < 2; ++f)
            a[4 + f] = *(const short8v*)(P.agg1b + (size_t)row_a * 64 + f * 32 + klane);
#pragma unroll
        for (int nt = 0; nt < 4; ++nt) {
            f32x4 acc = {0.0f, 0.0f, 0.0f, 0.0f};
#pragma unroll
            for (int f = 0; f < 6; ++f) {
                const short8v b =
                    *(const short8v*)(P.Wf1n + (size_t)(nt * 6 + f) * 512 + lane * 8);
                acc = __builtin_amdgcn_mfma_f32_16x16x32_bf16(a[f], b, acc, 0, 0, 0);
            }
            const int col = nt * 16 + (lane & 15);
            const int lr0 = wid * 16 + ((lane >> 4) << 2);
#pragma unroll
            for (int r = 0; r < 4; ++r)
                h1s[lr0 + r][col] = f2bf(selu_f(acc[r] + P.bn1[col]));
        }
        __syncthreads();
        short8v ha[2];
#pragma unroll
        for (int f = 0; f < 2; ++f)
            ha[f] = *(const short8v*)&h1s[wid * 16 + (lane & 15)][f * 32 + klane];
#pragma unroll
        for (int nt = 0; nt < 24; ++nt) {
            f32x4 acc = {0.0f, 0.0f, 0.0f, 0.0f};
#pragma unroll
            for (int f = 0; f < 2; ++f) {
                const short8v b =
                    *(const short8v*)(P.WfE + (size_t)(nt * 2 + f) * 512 + lane * 8);
                acc = __builtin_amdgcn_mfma_f32_16x16x32_bf16(ha[f], b, acc, 0, 0, 0);
            }
            const int col = nt * 16 + (lane & 15);
            const int r0 = row_base + ((lane >> 4) << 2);
#pragma unroll
            for (int r = 0; r < 4; ++r)
                P.RE[(size_t)(r0 + r) * 384 + col] = f2bf(acc[r]);
        }
    }
    gg.sync();

    // ===== P7: pfE — RE-side interpolation (PF.zw, QF.zw, Uf2) =====
    {
        const int w = bid * 4 + wid;          // 0..2047
        const unsigned lo = (unsigned)(lane * 2);
        for (int n = w; n < NF; n += 2048) {
            const float4 mi = P.meta[2 * n];
            const float4 mw = P.meta[2 * n + 1];
            const unsigned e0 = __float_as_uint(mi.x) * 384 + lo;
            const unsigned e1 = __float_as_uint(mi.y) * 384 + lo;
            const unsigned e2 = __float_as_uint(mi.z) * 384 + lo;
            const ushort2 p0 = *(const ushort2*)(P.RE + e0);
            const ushort2 p1 = *(const ushort2*)(P.RE + e1);
            const ushort2 p2 = *(const ushort2*)(P.RE + e2);
            const ushort2 q0 = *(const ushort2*)(P.RE + e0 + 128);
            const ushort2 q1 = *(const ushort2*)(P.RE + e1 + 128);
            const ushort2 q2 = *(const ushort2*)(P.RE + e2 + 128);
            const ushort2 u0 = *(const ushort2*)(P.RE + e0 + 256);
            const ushort2 u1 = *(const ushort2*)(P.RE + e1 + 256);
            const ushort2 u2 = *(const ushort2*)(P.RE + e2 + 256);
            const float2 b2 = *(const float2*)(P.be2 + lane * 2);
            ushort2 o;
            o.x = f2bf(mw.x * bf2f(p0.x) + mw.y * bf2f(p1.x) + mw.z * bf2f(p2.x));
            o.y = f2bf(mw.x * bf2f(p0.y) + mw.y * bf2f(p1.y) + mw.z * bf2f(p2.y));
            *(ushort2*)(P.PF + (size_t)n * 256 + lane * 4 + 2) = o;
            o.x = f2bf(mw.x * bf2f(q0.x) + mw.y * bf2f(q1.x) + mw.z * bf2f(q2.x) + b2.x);
            o.y = f2bf(mw.x * bf2f(q0.y) + mw.y * bf2f(q1.y) + mw.z * bf2f(q2.y) + b2.y);
            *(ushort2*)(P.QF + (size_t)n * 256 + lane * 4 + 2) = o;
            o.x = f2bf(mw.x * bf2f(u0.x) + mw.y * bf2f(u1.x) + mw.z * bf2f(u2.x));
            o.y = f2bf(mw.x * bf2f(u0.y) + mw.y * bf2f(u1.y) + mw.z * bf2f(u2.y));
            *(ushort2*)(P.Uf2 + (size_t)n * 128 + lo) = o;
        }
    }
    gg.sync();

    // ===== P8: aggBoth — one 8B gather per edge =====
    {
        const int w = bid * 4 + wid;          // 0..2047
        const unsigned lo4 = (unsigned)(lane * 4);
        const unsigned lo = (unsigned)(lane * 2);
        for (int n = w; n < NF; n += 2048) {
            const ushort4 qv = *(const ushort4*)(P.QF + (size_t)n * 256 + lo4);
            const float qSx = bf2f(qv.x), qSy = bf2f(qv.y);
            const float q2x = bf2f(qv.z), q2y = bf2f(qv.w);
            const int b1 = P.cntF[n];
            const int* bucket = P.srtF + n * CAPF;
            float aSx = 0.0f, aSy = 0.0f, a2x = 0.0f, a2y = 0.0f;
            int e = 0;
            for (; e + 8 <= b1; e += 8) {
                int s[8];
#pragma unroll
                for (int j = 0; j < 8; ++j) s[j] = bucket[e + j];
                ushort4 g[8];
#pragma unroll
                for (int j = 0; j < 8; ++j)
                    g[j] = *(const ushort4*)(P.PF + (unsigned)s[j] * 256u + lo4);
#pragma unroll
                for (int j = 0; j < 8; ++j) {
                    aSx += selu_f(bf2f(g[j].x) + qSx);
                    aSy += selu_f(bf2f(g[j].y) + qSy);
                    a2x += selu_f(bf2f(g[j].z) + q2x);
                    a2y += selu_f(bf2f(g[j].w) + q2y);
                }
            }
            if (e < b1) {
                int s[8];
                ushort4 g[8];
                const int m = b1 - e;
#pragma unroll
                for (int j = 0; j < 8; ++j)
                    s[j] = (j < m) ? bucket[e + j] : s[0];
#pragma unroll
                for (int j = 0; j < 8; ++j)
                    g[j] = *(const ushort4*)(P.PF + (unsigned)s[j] * 256u + lo4);
#pragma unroll
                for (int j = 0; j < 8; ++j) {
                    if (j < m) {
                        aSx += selu_f(bf2f(g[j].x) + qSx);
                        aSy += selu_f(bf2f(g[j].y) + qSy);
                        a2x += selu_f(bf2f(g[j].z) + q2x);
                        a2y += selu_f(bf2f(g[j].w) + q2y);
                    }
                }
            }
            ushort2 r;
            r.x = f2bf(aSx); r.y = f2bf(aSy);
            *(ushort2*)(P.aggS + (size_t)n * 128 + lo) = r;
            r.x = f2bf(a2x); r.y = f2bf(a2y);
            *(ushort2*)(P.agg2 + (size_t)n * 128 + lo) = r;
        }
    }
    gg.sync();

    // ===== P9: nodeF (512 blocks; tile = bid>>1, nt-half = bid&1) =====
    {
        const int klane = (lane >> 4) << 3;
        if (tid < 128) { s_red[tid] = 0.0f; s_red[128 + tid] = 0.0f; }
        __syncthreads();
        const int tile = bid >> 1;
        const int nt0 = (bid & 1) * 4;
        const int row_base = tile * 64 + wid * 16;
        const int row_a = row_base + (lane & 15);
        short8v aS[4], a2[4];
#pragma unroll
        for (int f = 0; f < 4; ++f) {
            aS[f] = *(const short8v*)(P.aggS + (size_t)row_a * 128 + f * 32 + klane);
            a2[f] = *(const short8v*)(P.agg2 + (size_t)row_a * 128 + f * 32 + klane);
        }
#pragma unroll
        for (int q = 0; q < 4; ++q) {
            const int nt = nt0 + q;
            f32x4 accS = {0.0f, 0.0f, 0.0f, 0.0f};
            f32x4 acc2 = {0.0f, 0.0f, 0.0f, 0.0f};
#pragma unroll
            for (int f = 0; f < 4; ++f) {
                const short8v bS =
                    *(const short8v*)(P.WfSn + (size_t)(nt * 4 + f) * 512 + lane * 8);
                const short8v b2 =
                    *(const short8v*)(P.Wf2n + (size_t)(nt * 4 + f) * 512 + lane * 8);
                accS = __builtin_amdgcn_mfma_f32_16x16x32_bf16(aS[f], bS, accS, 0, 0, 0);
                acc2 = __builtin_amdgcn_mfma_f32_16x16x32_bf16(a2[f], b2, acc2, 0, 0, 0);
            }
            const int col = nt * 16 + (lane & 15);
            const int r0 = row_base + ((lane >> 4) << 2);
            float lsum = 0.0f, lsq = 0.0f;
#pragma unroll
            for (int r = 0; r < 4; ++r) {
                const size_t o = (size_t)(r0 + r) * 128 + col;
                const float xs = selu_f(accS[r] + P.bnS[col] + bf2f(P.UfS[o]));
                const float hh = selu_f(acc2[r] + P.bn2[col] + bf2f(P.Uf2[o]));
                const float v = hh + xs;
                P.outp[o] = v;
                lsum += v; lsq += v * v;
            }
            atomicAdd(&s_red[nt * 16 + (lane & 15)], lsum);
            atomicAdd(&s_red[128 + nt * 16 + (lane & 15)], lsq);
        }
        __syncthreads();
        if (tid < 128) {
            atomicAdd(&P.stats[tid], s_red[tid]);
            atomicAdd(&P.stats[128 + tid], s_red[128 + tid]);
        }
    }
    gg.sync();

    // ===== P10: BN normalize + SELU =====
    {
        const float invn = 1.0f / (float)NF;
        for (int i = bid * 256 + tid; i < NF * 128; i += GRID * 256) {
            const int c = i & 127;
            const float mu = P.stats[c] * invn;
            const float var = P.stats[128 + c] * invn - mu * mu;
            const float r = rsqrtf(var + 1e-5f);
            const float v = (P.outp[i] - mu) * r * P.gamma[c] + P.beta[c];
            P.outp[i] = selu_f(v);
        }
    }
}

// ---------------------------------------------------------------------------
extern "C" void kernel_launch(void* const* d_in, const int* in_sizes, int n_in,
                              void* d_out, int out_size, void* d_ws, size_t ws_size,
                              hipStream_t stream) {
    KParams P;
    P.x     = (const float*)d_in[0];
    P.pos_c = (const float*)d_in[1];
    P.pos_f = (const float*)d_in[2];
    P.ei_c  = (const int*)d_in[3];
    P.ei_f  = (const int*)d_in[4];
    P.We1 = (const float*)d_in[5];
    P.be1 = (const float*)d_in[6];
    P.Wn1 = (const float*)d_in[7];
    P.bn1 = (const float*)d_in[8];
    P.We2 = (const float*)d_in[9];
    P.be2 = (const float*)d_in[10];
    P.Wn2 = (const float*)d_in[11];
    P.bn2 = (const float*)d_in[12];
    P.WeS = (const float*)d_in[13];
    P.beS = (const float*)d_in[14];
    P.WnS = (const float*)d_in[15];
    P.bnS = (const float*)d_in[16];
    P.gamma = (const float*)d_in[17];
    P.beta  = (const float*)d_in[18];

    char* w = (char*)d_ws;
    size_t o = 0;
    auto alloc = [&](size_t bytes) { void* p = w + o; o += (bytes + 255) & ~(size_t)255; return p; };
    P.meta  = (float4*)alloc((size_t)NF * 2 * sizeof(float4));
    P.RA    = (ushort_t*)alloc((size_t)NC * 512 * 2);
    P.RE    = (ushort_t*)alloc((size_t)NC * 384 * 2);
    P.PF    = (ushort_t*)alloc((size_t)NF * 256 * 2);
    P.QF    = (ushort_t*)alloc((size_t)NF * 256 * 2);
    P.UfS   = (ushort_t*)alloc((size_t)NF * 128 * 2);
    P.Uf2   = (ushort_t*)alloc((size_t)NF * 128 * 2);
    P.aggS  = (ushort_t*)alloc((size_t)NF * 128 * 2);
    P.agg2  = (ushort_t*)alloc((size_t)NF * 128 * 2);
    P.agg1b = (ushort_t*)alloc((size_t)NC * 64 * 2);
    P.xb    = (ushort_t*)alloc((size_t)NC * 128 * 2);
    P.WfA   = (ushort_t*)alloc(65536 * 2);
    P.WfE   = (ushort_t*)alloc(24576 * 2);
    P.WfSn  = (ushort_t*)alloc(16384 * 2);
    P.Wf1n  = (ushort_t*)alloc(12288 * 2);
    P.Wf2n  = (ushort_t*)alloc(16384 * 2);
    P.cntF  = (int*)alloc((size_t)NF * sizeof(int));
    P.srtF  = (int*)alloc((size_t)NF * CAPF * sizeof(int));
    P.cntC  = (int*)alloc((size_t)NC * sizeof(int));
    P.srtC  = (int*)alloc((size_t)NC * CAPC * sizeof(int));
    P.cntG  = (int*)alloc((size_t)NCELL * sizeof(int));
    P.grecs = (float4*)alloc((size_t)NCELL * CAPG * sizeof(float4));
    P.stats = (float*)alloc(256 * sizeof(float));
    P.outp  = (float*)d_out;

    void* args[] = { &P };
    hipLaunchCooperativeKernel((const void*)mega_kernel, dim3(GRID), dim3(256),
                               args, 0, stream);
}

// Round 17
// 143.914 us; speedup vs baseline: 4.7422x; 4.7422x over previous
//
#include <hip/hip_runtime.h>

// ---------------------------------------------------------------------------
// Res_up block, round 17: revert to round-14 optimum (9 dispatches, 144 µs).
// Round 15/16's cooperative mega-kernel was 4.7x slower: grid.sync on 8
// non-coherent XCDs forces L2 drain/invalidate per phase (96MB FETCH + 100MB
// WRITE per replay). Small back-to-back dispatches keep L2 warm.
// Sizes fixed: Nc=4096, Nf=16384, Ec=65536, Ef=262144, Cin=128, Ch=64, Co=128.
// ---------------------------------------------------------------------------

#define SELU_SCALE 1.0507009873554805f
#define SELU_ALPHA 1.6732632423543772f

static constexpr int NC = 4096, NF = 16384, EC = 65536, EF = 262144;
static constexpr int G = 32, NCELL = G * G;
static constexpr int CAPF = 64, CAPC = 64, CAPG = 32;

typedef __attribute__((ext_vector_type(8))) short short8v;
typedef __attribute__((ext_vector_type(4))) float f32x4;
typedef unsigned short ushort_t;
typedef unsigned long long u64;

__device__ __forceinline__ float selu_f(float x) {
    return x > 0.0f ? SELU_SCALE * x
                    : SELU_SCALE * SELU_ALPHA * (__expf(x) - 1.0f);
}
__device__ __forceinline__ ushort_t f2bf(float f) {
    unsigned u = __float_as_uint(f);
    u += 0x7FFFu + ((u >> 16) & 1u);
    return (ushort_t)(u >> 16);
}
__device__ __forceinline__ float bf2f(ushort_t u) {
    return __uint_as_float(((unsigned)u) << 16);
}
__device__ __forceinline__ int cell_of(float2 p) {
    int cx = (int)(p.x * (float)G); cx = cx > G - 1 ? G - 1 : cx;
    int cy = (int)(p.y * (float)G); cy = cy > G - 1 ? G - 1 : cy;
    return cy * G + cx;
}
__device__ __forceinline__ void ins3(u64& a0, u64& a1, u64& a2, u64 v) {
    if (v < a2) {
        if (v < a1) {
            a2 = a1;
            if (v < a0) { a1 = a0; a0 = v; } else a1 = v;
        } else a2 = v;
    }
}

// ---------------------------------------------------------------------------
// Fragment-major weight writer: Wf[(ntile*KC+kc)*512 + lane*8 + e] = W[k][col]
// ---------------------------------------------------------------------------
template <int K, typename F>
__device__ __forceinline__ void wfrag(F getw, ushort_t* __restrict__ dst, int idx) {
    constexpr int KC = K / 32;
    const int f = idx >> 9;
    const int r = idx & 511;
    const int lane = r >> 3;
    const int e = r & 7;
    const int ntile = f / KC;
    const int kc = f - ntile * KC;
    const int k = kc * 32 + ((lane >> 4) << 3) + e;
    const int col = ntile * 16 + (lane & 15);
    dst[idx] = f2bf(getw(k, col));
}

// ---------------------------------------------------------------------------
// prep: x->bf16, 5 weight-frag buffers, zero cnt/stats.
// ---------------------------------------------------------------------------
__global__ __launch_bounds__(256) void prep_kernel(
    const float* __restrict__ x, ushort_t* __restrict__ xb,
    const float* __restrict__ WeS, const float* __restrict__ WnS,
    const float* __restrict__ We1, const float* __restrict__ We2,
    const float* __restrict__ Wn2, const float* __restrict__ Wn1,
    ushort_t* __restrict__ WfA, ushort_t* __restrict__ WfE,
    ushort_t* __restrict__ WfSn, ushort_t* __restrict__ Wf1n,
    ushort_t* __restrict__ Wf2n,
    int* __restrict__ cntF, int* __restrict__ cntC, int* __restrict__ cntG,
    float* __restrict__ stats) {
    int i = blockIdx.x * 256 + threadIdx.x;
    if (i < NC * 128) { xb[i] = f2bf(x[i]); return; }
    i -= NC * 128;
    if (i < 65536) {   // RA weights: K=128, N=512
        wfrag<128>([&](int k, int j) {
            return j < 128 ? WeS[k * 128 + j]
                 : j < 256 ? WeS[(128 + k) * 128 + (j - 128)]
                 : j < 384 ? WnS[k * 128 + (j - 256)]
                 : j < 448 ? We1[k * 64 + (j - 384)]
                           : We1[(128 + k) * 64 + (j - 448)];
        }, WfA, i);
        return;
    }
    i -= 65536;
    if (i < 24576) {   // RE weights: K=64, N=384
        wfrag<64>([&](int k, int j) {
            return j < 128 ? We2[k * 128 + j]
                 : j < 256 ? We2[(64 + k) * 128 + (j - 128)]
                           : Wn2[k * 128 + (j - 256)];
        }, WfE, i);
        return;
    }
    i -= 24576;
    if (i < 16384) {   // nodeS: WnS bottom half, K=128, N=128
        wfrag<128>([&](int k, int j) { return WnS[(128 + k) * 128 + j]; }, WfSn, i);
        return;
    }
    i -= 16384;
    if (i < 12288) {   // node1: full Wn1, K=192, N=64
        wfrag<192>([&](int k, int j) { return Wn1[k * 64 + j]; }, Wf1n, i);
        return;
    }
    i -= 12288;
    if (i < 16384) {   // nodeH: Wn2 bottom, K=128, N=128
        wfrag<128>([&](int k, int j) { return Wn2[(64 + k) * 128 + j]; }, Wf2n, i);
        return;
    }
    i -= 16384;
    if (i < NF) { cntF[i] = 0; return; }
    i -= NF;
    if (i < NC) { cntC[i] = 0; return; }
    i -= NC;
    if (i < NCELL) { cntG[i] = 0; return; }
    i -= NCELL;
    if (i < 256) { stats[i] = 0.0f; return; }
}

// ---------------------------------------------------------------------------
// Direct scatter into fixed-stride buckets (counts double as cursors).
// ---------------------------------------------------------------------------
__global__ __launch_bounds__(256) void scatter_kernel(
    const int* __restrict__ ei_f, const int* __restrict__ ei_c,
    const float* __restrict__ pos_c,
    int* __restrict__ cntF, int* __restrict__ srtF,
    int* __restrict__ cntC, int* __restrict__ srtC,
    int* __restrict__ cntG, float4* __restrict__ grecs) {
    int i = blockIdx.x * 256 + threadIdx.x;
    if (i < EF) {
        const int dst = ei_f[EF + i];
        const int slot = atomicAdd(&cntF[dst], 1);
        srtF[dst * CAPF + slot] = ei_f[i];
        return;
    }
    i -= EF;
    if (i < EC) {
        const int dst = ei_c[EC + i];
        const int slot = atomicAdd(&cntC[dst], 1);
        srtC[dst * CAPC + slot] = ei_c[i];
        return;
    }
    i -= EC;
    if (i < NC) {
        const float2 p = ((const float2*)pos_c)[i];
        const int c = cell_of(p);
        const int slot = atomicAdd(&cntG[c], 1);
        float4 rec;
        rec.x = p.x; rec.y = p.y; rec.z = __int_as_float(i); rec.w = 0.0f;
        grecs[c * CAPG + slot] = rec;
    }
}

// ---------------------------------------------------------------------------
// Fused: blocks 0..255 = RA GEMM (4096x512x128, bf16 out);
// blocks 256..767 = grid-kNN, 8 lanes per fine point (bucketed cells).
// meta[2t] = idx bits (as float), meta[2t+1] = weights.
// ---------------------------------------------------------------------------
__global__ __launch_bounds__(256) void gemmA_knn_kernel(
    const ushort_t* __restrict__ xb, const ushort_t* __restrict__ WfA,
    ushort_t* __restrict__ RA,
    const float* __restrict__ pos_f, const float4* __restrict__ grecs,
    const int* __restrict__ cntG, float4* __restrict__ meta) {
    const int bid = blockIdx.x;
    const int tid = threadIdx.x;
    if (bid < 256) {
        const int wid = tid >> 6, lane = tid & 63;
        const int bx = bid >> 2, by = bid & 3;
        const int row_base = bx * 64 + wid * 16;
        const int row_a = row_base + (lane & 15);
        const int klane = (lane >> 4) << 3;
        short8v a[4];
#pragma unroll
        for (int f = 0; f < 4; ++f)
            a[f] = *(const short8v*)(xb + (size_t)row_a * 128 + f * 32 + klane);
#pragma unroll
        for (int nt = 0; nt < 8; ++nt) {
            const int ntg = by * 8 + nt;
            f32x4 acc = {0.0f, 0.0f, 0.0f, 0.0f};
#pragma unroll
            for (int f = 0; f < 4; ++f) {
                const short8v b =
                    *(const short8v*)(WfA + (size_t)(ntg * 4 + f) * 512 + lane * 8);
                acc = __builtin_amdgcn_mfma_f32_16x16x32_bf16(a[f], b, acc, 0, 0, 0);
            }
            const int col = ntg * 16 + (lane & 15);
            const int r0 = row_base + ((lane >> 4) << 2);
#pragma unroll
            for (int r = 0; r < 4; ++r)
                RA[(size_t)(r0 + r) * 512 + col] = f2bf(acc[r]);
        }
    } else {
        const int g8 = (bid - 256) * 256 + tid;    // 131072 = 8 * NF
        const int t = g8 >> 3;
        const int sub = g8 & 7;
        const float2 p = ((const float2*)pos_f)[t];
        int cx = (int)(p.x * (float)G); cx = cx > G - 1 ? G - 1 : cx;
        int cy = (int)(p.y * (float)G); cy = cy > G - 1 ? G - 1 : cy;
        const float h = 1.0f / (float)G;

        u64 b0 = ~0ull, b1 = ~0ull, b2 = ~0ull;

        auto scan_cell = [&](int c, u64& t0, u64& t1, u64& t2) {
            const int cn = cntG[c];
            for (int i = sub; i < cn; i += 8) {
                const float4 q = grecs[(c << 5) + i];
                const float dx = p.x - q.x;
                const float dy = p.y - q.y;
                const float d = dx * dx + dy * dy;
                ins3(t0, t1, t2, ((u64)__float_as_uint(d) << 32) |
                                 (u64)__float_as_uint(q.z));
            }
        };

        {
            const int xx0 = cx - 1 < 0 ? 0 : cx - 1;
            const int xx1 = cx + 1 > G - 1 ? G - 1 : cx + 1;
            const int yy0 = cy - 1 < 0 ? 0 : cy - 1;
            const int yy1 = cy + 1 > G - 1 ? G - 1 : cy + 1;
            for (int yy = yy0; yy <= yy1; ++yy)
                for (int xx = xx0; xx <= xx1; ++xx)
                    scan_cell(yy * G + xx, b0, b1, b2);
#pragma unroll
            for (int mk = 1; mk <= 4; mk <<= 1) {
                const u64 e0 = __shfl_xor(b0, mk);
                const u64 e1 = __shfl_xor(b1, mk);
                const u64 e2 = __shfl_xor(b2, mk);
                ins3(b0, b1, b2, e0);
                ins3(b0, b1, b2, e1);
                ins3(b0, b1, b2, e2);
            }
        }

        for (int r = 2; r < G; ++r) {
            const float bd = __uint_as_float((unsigned)(b2 >> 32));
            const float lim = (float)(r - 1) * h;
            if (bd < lim * lim) break;     // NaN-safe: continues while unfilled
            u64 c0 = ~0ull, c1 = ~0ull, c2 = ~0ull;
            auto scan_full = [&](int c) {   // whole cell, this lane alone
                const int cn = cntG[c];
                for (int i = 0; i < cn; ++i) {
                    const float4 q = grecs[(c << 5) + i];
                    const float dx = p.x - q.x;
                    const float dy = p.y - q.y;
                    const float d = dx * dx + dy * dy;
                    ins3(c0, c1, c2, ((u64)__float_as_uint(d) << 32) |
                                     (u64)__float_as_uint(q.z));
                }
            };
            const int side = sub & 3, phase = sub >> 2;
            const int x0 = cx - r < 0 ? 0 : cx - r;
            const int x1 = cx + r > G - 1 ? G - 1 : cx + r;
            const int yi0 = cy - r + 1 < 0 ? 0 : cy - r + 1;
            const int yi1 = cy + r - 1 > G - 1 ? G - 1 : cy + r - 1;
            if (side == 0) {
                if (cy - r >= 0)
                    for (int xx = x0 + phase; xx <= x1; xx += 2)
                        scan_full((cy - r) * G + xx);
            } else if (side == 1) {
                if (cy + r <= G - 1)
                    for (int xx = x0 + phase; xx <= x1; xx += 2)
                        scan_full((cy + r) * G + xx);
            } else if (side == 2) {
                if (cx - r >= 0)
                    for (int yy = yi0 + phase; yy <= yi1; yy += 2)
                        scan_full(yy * G + cx - r);
            } else {
                if (cx + r <= G - 1)
                    for (int yy = yi0 + phase; yy <= yi1; yy += 2)
                        scan_full(yy * G + cx + r);
            }
#pragma unroll
            for (int mk = 1; mk <= 4; mk <<= 1) {
                const u64 e0 = __shfl_xor(c0, mk);
                const u64 e1 = __shfl_xor(c1, mk);
                const u64 e2 = __shfl_xor(c2, mk);
                ins3(c0, c1, c2, e0);
                ins3(c0, c1, c2, e1);
                ins3(c0, c1, c2, e2);
            }
            ins3(b0, b1, b2, c0);
            ins3(b0, b1, b2, c1);
            ins3(b0, b1, b2, c2);
        }

        if (sub == 0) {
            const float d0 = __uint_as_float((unsigned)(b0 >> 32));
            const float d1 = __uint_as_float((unsigned)(b1 >> 32));
            const float d2 = __uint_as_float((unsigned)(b2 >> 32));
            const float w0 = 1.0f / fmaxf(d0, 1e-16f);
            const float w1 = 1.0f / fmaxf(d1, 1e-16f);
            const float w2 = 1.0f / fmaxf(d2, 1e-16f);
            const float s = 1.0f / (w0 + w1 + w2);
            float4 mi;
            mi.x = __uint_as_float((unsigned)(b0 & 0xffffffffu));
            mi.y = __uint_as_float((unsigned)(b1 & 0xffffffffu));
            mi.z = __uint_as_float((unsigned)(b2 & 0xffffffffu));
            mi.w = 0.0f;
            float4 mw;
            mw.x = w0 * s; mw.y = w1 * s; mw.z = w2 * s; mw.w = 0.0f;
            meta[2 * t] = mi;
            meta[2 * t + 1] = mw;
        }
    }
}

// ---------------------------------------------------------------------------
// agg1: coarse aggregation (RA cols 384=P1, 448=Q1), wave-per-node, unroll 4.
// ---------------------------------------------------------------------------
__global__ __launch_bounds__(256) void agg1_kernel(
    const ushort_t* __restrict__ R, const int* __restrict__ cntC,
    const int* __restrict__ srtC, const float* __restrict__ beC,
    ushort_t* __restrict__ aggC) {
    const int n = blockIdx.x * 4 + (threadIdx.x >> 6);
    const int lane = threadIdx.x & 63;
    const int b1 = cntC[n];
    const int* bucket = srtC + n * CAPC;
    const float q = bf2f(R[(unsigned)n * 512u + 448 + lane]) + beC[lane];
    const unsigned clo = 384u + (unsigned)lane;
    float s = 0.0f;
    int e = 0;
    for (; e + 4 <= b1; e += 4) {
        const int s0 = bucket[e], s1 = bucket[e + 1];
        const int s2 = bucket[e + 2], s3 = bucket[e + 3];
        const ushort_t v0 = R[(unsigned)s0 * 512u + clo];
        const ushort_t v1 = R[(unsigned)s1 * 512u + clo];
        const ushort_t v2 = R[(unsigned)s2 * 512u + clo];
        const ushort_t v3 = R[(unsigned)s3 * 512u + clo];
        s += selu_f(bf2f(v0) + q);
        s += selu_f(bf2f(v1) + q);
        s += selu_f(bf2f(v2) + q);
        s += selu_f(bf2f(v3) + q);
    }
    for (; e < b1; ++e)
        s += selu_f(bf2f(R[(unsigned)bucket[e] * 512u + clo]) + q);
    aggC[(size_t)n * 64 + lane] = f2bf(s);
}

// ---------------------------------------------------------------------------
// nodeD: h1 = selu(concat(xb,agg1b)@Wn1 + bn1) in LDS, then RE = h1 @ WfE.
// ---------------------------------------------------------------------------
__global__ __launch_bounds__(256) void nodeD_kernel(
    const ushort_t* __restrict__ xb, const ushort_t* __restrict__ agg1b,
    const ushort_t* __restrict__ Wf1n, const float* __restrict__ bn1,
    const ushort_t* __restrict__ WfE, ushort_t* __restrict__ RE) {
    __shared__ ushort_t h1s[64][72];
    const int tid = threadIdx.x;
    const int wid = tid >> 6, lane = tid & 63;
    const int klane = (lane >> 4) << 3;
    const int row_base = blockIdx.x * 64 + wid * 16;
    const int row_a = row_base + (lane & 15);
    short8v a[6];
#pragma unroll
    for (int f = 0; f < 4; ++f)
        a[f] = *(const short8v*)(xb + (size_t)row_a * 128 + f * 32 + klane);
#pragma unroll
    for (int f = 0; f < 2; ++f)
        a[4 + f] = *(const short8v*)(agg1b + (size_t)row_a * 64 + f * 32 + klane);
#pragma unroll
    for (int nt = 0; nt < 4; ++nt) {
        f32x4 acc = {0.0f, 0.0f, 0.0f, 0.0f};
#pragma unroll
        for (int f = 0; f < 6; ++f) {
            const short8v b =
                *(const short8v*)(Wf1n + (size_t)(nt * 6 + f) * 512 + lane * 8);
            acc = __builtin_amdgcn_mfma_f32_16x16x32_bf16(a[f], b, acc, 0, 0, 0);
        }
        const int col = nt * 16 + (lane & 15);
        const int lr0 = wid * 16 + ((lane >> 4) << 2);
#pragma unroll
        for (int r = 0; r < 4; ++r)
            h1s[lr0 + r][col] = f2bf(selu_f(acc[r] + bn1[col]));
    }
    __syncthreads();
    short8v ha[2];
#pragma unroll
    for (int f = 0; f < 2; ++f)
        ha[f] = *(const short8v*)&h1s[wid * 16 + (lane & 15)][f * 32 + klane];
#pragma unroll
    for (int nt = 0; nt < 24; ++nt) {
        f32x4 acc = {0.0f, 0.0f, 0.0f, 0.0f};
#pragma unroll
        for (int f = 0; f < 2; ++f) {
            const short8v b =
                *(const short8v*)(WfE + (size_t)(nt * 2 + f) * 512 + lane * 8);
            acc = __builtin_amdgcn_mfma_f32_16x16x32_bf16(ha[f], b, acc, 0, 0, 0);
        }
        const int col = nt * 16 + (lane & 15);
        const int r0 = row_base + ((lane >> 4) << 2);
#pragma unroll
        for (int r = 0; r < 4; ++r)
            RE[(size_t)(r0 + r) * 384 + col] = f2bf(acc[r]);
    }
}

// ---------------------------------------------------------------------------
// pfBoth: per fine node, interpolate P/Q/U from RA (512) and RE (384).
// Writes interleaved PF/QF (ushort4: {S.x,S.y,2.x,2.y}) and UfS/Uf2.
// ---------------------------------------------------------------------------
__global__ __launch_bounds__(256) void pfboth_kernel(
    const ushort_t* __restrict__ RA, const ushort_t* __restrict__ RE,
    const float4* __restrict__ meta,
    const float* __restrict__ beS, const float* __restrict__ be2,
    ushort_t* __restrict__ PF, ushort_t* __restrict__ QF,
    ushort_t* __restrict__ UfS, ushort_t* __restrict__ Uf2) {
    const int gid = blockIdx.x * 256 + threadIdx.x;
    const int n = gid >> 6, lane = gid & 63;
    const float4 mi = meta[2 * n];
    const float4 mw = meta[2 * n + 1];
    const unsigned lo = (unsigned)(lane * 2);
    const unsigned i0 = __float_as_uint(mi.x);
    const unsigned i1 = __float_as_uint(mi.y);
    const unsigned i2 = __float_as_uint(mi.z);
    const unsigned a0 = i0 * 512 + lo, a1 = i1 * 512 + lo, a2 = i2 * 512 + lo;
    const unsigned e0 = i0 * 384 + lo, e1 = i1 * 384 + lo, e2 = i2 * 384 + lo;
    const ushort2 pA0 = *(const ushort2*)(RA + a0);
    const ushort2 pA1 = *(const ushort2*)(RA + a1);
    const ushort2 pA2 = *(const ushort2*)(RA + a2);
    const ushort2 qA0 = *(const ushort2*)(RA + a0 + 128);
    const ushort2 qA1 = *(const ushort2*)(RA + a1 + 128);
    const ushort2 qA2 = *(const ushort2*)(RA + a2 + 128);
    const ushort2 uA0 = *(const ushort2*)(RA + a0 + 256);
    const ushort2 uA1 = *(const ushort2*)(RA + a1 + 256);
    const ushort2 uA2 = *(const ushort2*)(RA + a2 + 256);
    const ushort2 pE0 = *(const ushort2*)(RE + e0);
    const ushort2 pE1 = *(const ushort2*)(RE + e1);
    const ushort2 pE2 = *(const ushort2*)(RE + e2);
    const ushort2 qE0 = *(const ushort2*)(RE + e0 + 128);
    const ushort2 qE1 = *(const ushort2*)(RE + e1 + 128);
    const ushort2 qE2 = *(const ushort2*)(RE + e2 + 128);
    const ushort2 uE0 = *(const ushort2*)(RE + e0 + 256);
    const ushort2 uE1 = *(const ushort2*)(RE + e1 + 256);
    const ushort2 uE2 = *(const ushort2*)(RE + e2 + 256);
    const float2 bS = *(const float2*)(beS + lane * 2);
    const float2 b2 = *(const float2*)(be2 + lane * 2);
    ushort4 pf, qf;
    pf.x = f2bf(mw.x * bf2f(pA0.x) + mw.y * bf2f(pA1.x) + mw.z * bf2f(pA2.x));
    pf.y = f2bf(mw.x * bf2f(pA0.y) + mw.y * bf2f(pA1.y) + mw.z * bf2f(pA2.y));
    pf.z = f2bf(mw.x * bf2f(pE0.x) + mw.y * bf2f(pE1.x) + mw.z * bf2f(pE2.x));
    pf.w = f2bf(mw.x * bf2f(pE0.y) + mw.y * bf2f(pE1.y) + mw.z * bf2f(pE2.y));
    *(ushort4*)(PF + (size_t)n * 256 + lane * 4) = pf;
    qf.x = f2bf(mw.x * bf2f(qA0.x) + mw.y * bf2f(qA1.x) + mw.z * bf2f(qA2.x) + bS.x);
    qf.y = f2bf(mw.x * bf2f(qA0.y) + mw.y * bf2f(qA1.y) + mw.z * bf2f(qA2.y) + bS.y);
    qf.z = f2bf(mw.x * bf2f(qE0.x) + mw.y * bf2f(qE1.x) + mw.z * bf2f(qE2.x) + b2.x);
    qf.w = f2bf(mw.x * bf2f(qE0.y) + mw.y * bf2f(qE1.y) + mw.z * bf2f(qE2.y) + b2.y);
    *(ushort4*)(QF + (size_t)n * 256 + lane * 4) = qf;
    ushort2 o;
    o.x = f2bf(mw.x * bf2f(uA0.x) + mw.y * bf2f(uA1.x) + mw.z * bf2f(uA2.x));
    o.y = f2bf(mw.x * bf2f(uA0.y) + mw.y * bf2f(uA1.y) + mw.z * bf2f(uA2.y));
    *(ushort2*)(UfS + (size_t)n * 128 + lo) = o;
    o.x = f2bf(mw.x * bf2f(uE0.x) + mw.y * bf2f(uE1.x) + mw.z * bf2f(uE2.x));
    o.y = f2bf(mw.x * bf2f(uE0.y) + mw.y * bf2f(uE1.y) + mw.z * bf2f(uE2.y));
    *(ushort2*)(Uf2 + (size_t)n * 128 + lo) = o;
}

// ---------------------------------------------------------------------------
// aggBoth: one edge traversal, both aggregations, ONE 8B gather per edge.
// ---------------------------------------------------------------------------
__global__ __launch_bounds__(256) void aggboth_kernel(
    const ushort_t* __restrict__ PF, const ushort_t* __restrict__ QF,
    const int* __restrict__ cntF, const int* __restrict__ srtF,
    ushort_t* __restrict__ aggS, ushort_t* __restrict__ agg2) {
    const int n = blockIdx.x * 4 + (threadIdx.x >> 6);
    const int lane = threadIdx.x & 63;
    const unsigned lo4 = (unsigned)(lane * 4);
    const ushort4 qv = *(const ushort4*)(QF + (size_t)n * 256 + lo4);
    const float qSx = bf2f(qv.x), qSy = bf2f(qv.y);
    const float q2x = bf2f(qv.z), q2y = bf2f(qv.w);
    const int b1 = cntF[n];
    const int* bucket = srtF + n * CAPF;
    float aSx = 0.0f, aSy = 0.0f, a2x = 0.0f, a2y = 0.0f;
    int e = 0;
    for (; e + 8 <= b1; e += 8) {
        int s[8];
#pragma unroll
        for (int j = 0; j < 8; ++j) s[j] = bucket[e + j];
        ushort4 g[8];
#pragma unroll
        for (int j = 0; j < 8; ++j)
            g[j] = *(const ushort4*)(PF + (unsigned)s[j] * 256u + lo4);
#pragma unroll
        for (int j = 0; j < 8; ++j) {
            aSx += selu_f(bf2f(g[j].x) + qSx);
            aSy += selu_f(bf2f(g[j].y) + qSy);
            a2x += selu_f(bf2f(g[j].z) + q2x);
            a2y += selu_f(bf2f(g[j].w) + q2y);
        }
    }
    if (e < b1) {
        int s[8];
        ushort4 g[8];
        const int m = b1 - e;
#pragma unroll
        for (int j = 0; j < 8; ++j)
            s[j] = (j < m) ? bucket[e + j] : s[0];
#pragma unroll
        for (int j = 0; j < 8; ++j)
            g[j] = *(const ushort4*)(PF + (unsigned)s[j] * 256u + lo4);
#pragma unroll
        for (int j = 0; j < 8; ++j) {
            if (j < m) {
                aSx += selu_f(bf2f(g[j].x) + qSx);
                aSy += selu_f(bf2f(g[j].y) + qSy);
                a2x += selu_f(bf2f(g[j].z) + q2x);
                a2y += selu_f(bf2f(g[j].w) + q2y);
            }
        }
    }
    const unsigned lo = (unsigned)(lane * 2);
    ushort2 r;
    r.x = f2bf(aSx); r.y = f2bf(aSy);
    *(ushort2*)(aggS + (size_t)n * 128 + lo) = r;
    r.x = f2bf(a2x); r.y = f2bf(a2y);
    *(ushort2*)(agg2 + (size_t)n * 128 + lo) = r;
}

// ---------------------------------------------------------------------------
// nodeFinal: x_skip = selu(aggS@WfSn + UfS + bnS) (registers)
//            h      = selu(agg2@Wf2n + Uf2 + bn2)
//            v = h + x_skip -> outp; BN stats accumulated.
// ---------------------------------------------------------------------------
__global__ __launch_bounds__(256) void nodeF_kernel(
    const ushort_t* __restrict__ aggS, const ushort_t* __restrict__ WfSn,
    const float* __restrict__ bnS, const ushort_t* __restrict__ UfS,
    const ushort_t* __restrict__ agg2, const ushort_t* __restrict__ Wf2n,
    const float* __restrict__ bn2, const ushort_t* __restrict__ Uf2,
    float* __restrict__ outp, float* __restrict__ stats) {
    __shared__ float s_sum[128], s_sq[128];
    const int tid = threadIdx.x;
    const int wid = tid >> 6, lane = tid & 63;
    const int klane = (lane >> 4) << 3;
    if (tid < 128) { s_sum[tid] = 0.0f; s_sq[tid] = 0.0f; }
    __syncthreads();
    const int row_base = blockIdx.x * 64 + wid * 16;
    const int row_a = row_base + (lane & 15);
    short8v aS[4], a2[4];
#pragma unroll
    for (int f = 0; f < 4; ++f) {
        aS[f] = *(const short8v*)(aggS + (size_t)row_a * 128 + f * 32 + klane);
        a2[f] = *(const short8v*)(agg2 + (size_t)row_a * 128 + f * 32 + klane);
    }
#pragma unroll
    for (int nt = 0; nt < 8; ++nt) {
        f32x4 accS = {0.0f, 0.0f, 0.0f, 0.0f};
        f32x4 acc2 = {0.0f, 0.0f, 0.0f, 0.0f};
#pragma unroll
        for (int f = 0; f < 4; ++f) {
            const short8v bS =
                *(const short8v*)(WfSn + (size_t)(nt * 4 + f) * 512 + lane * 8);
            const short8v b2 =
                *(const short8v*)(Wf2n + (size_t)(nt * 4 + f) * 512 + lane * 8);
            accS = __builtin_amdgcn_mfma_f32_16x16x32_bf16(aS[f], bS, accS, 0, 0, 0);
            acc2 = __builtin_amdgcn_mfma_f32_16x16x32_bf16(a2[f], b2, acc2, 0, 0, 0);
        }
        const int col = nt * 16 + (lane & 15);
        const int r0 = row_base + ((lane >> 4) << 2);
        float lsum = 0.0f, lsq = 0.0f;
#pragma unroll
        for (int r = 0; r < 4; ++r) {
            const size_t o = (size_t)(r0 + r) * 128 + col;
            const float xs = selu_f(accS[r] + bnS[col] + bf2f(UfS[o]));
            const float hh = selu_f(acc2[r] + bn2[col] + bf2f(Uf2[o]));
            const float v = hh + xs;
            outp[o] = v;
            lsum += v; lsq += v * v;
        }
        atomicAdd(&s_sum[nt * 16 + (lane & 15)], lsum);
        atomicAdd(&s_sq[nt * 16 + (lane & 15)], lsq);
    }
    __syncthreads();
    if (tid < 128) {
        atomicAdd(&stats[tid], s_sum[tid]);
        atomicAdd(&stats[128 + tid], s_sq[tid]);
    }
}

// ---------------------------------------------------------------------------
// BN normalize + SELU, in place on d_out.
// ---------------------------------------------------------------------------
__global__ __launch_bounds__(256) void bn_kernel(
    float* __restrict__ out, const float* __restrict__ stats,
    const float* __restrict__ gamma, const float* __restrict__ beta, int Nn) {
    const int i = blockIdx.x * blockDim.x + threadIdx.x;
    const int c = i & 127;
    const float invn = 1.0f / (float)Nn;
    float mu = stats[c] * invn;
    float var = stats[128 + c] * invn - mu * mu;
    float r = rsqrtf(var + 1e-5f);
    float v = (out[i] - mu) * r * gamma[c] + beta[c];
    out[i] = selu_f(v);
}

// ---------------------------------------------------------------------------
extern "C" void kernel_launch(void* const* d_in, const int* in_sizes, int n_in,
                              void* d_out, int out_size, void* d_ws, size_t ws_size,
                              hipStream_t stream) {
    const float* x     = (const float*)d_in[0];
    const float* pos_c = (const float*)d_in[1];
    const float* pos_f = (const float*)d_in[2];
    const int*   ei_c  = (const int*)d_in[3];
    const int*   ei_f  = (const int*)d_in[4];
    const float* We1 = (const float*)d_in[5];
    const float* be1 = (const float*)d_in[6];
    const float* Wn1 = (const float*)d_in[7];
    const float* bn1 = (const float*)d_in[8];
    const float* We2 = (const float*)d_in[9];
    const float* be2 = (const float*)d_in[10];
    const float* Wn2 = (const float*)d_in[11];
    const float* bn2 = (const float*)d_in[12];
    const float* WeS = (const float*)d_in[13];
    const float* beS = (const float*)d_in[14];
    const float* WnS = (const float*)d_in[15];
    const float* bnS = (const float*)d_in[16];
    const float* gamma = (const float*)d_in[17];
    const float* beta  = (const float*)d_in[18];

    char* w = (char*)d_ws;
    size_t o = 0;
    auto alloc = [&](size_t bytes) { void* p = w + o; o += (bytes + 255) & ~(size_t)255; return p; };
    float4*   meta    = (float4*)alloc((size_t)NF * 2 * sizeof(float4));
    ushort_t* RA      = (ushort_t*)alloc((size_t)NC * 512 * 2);
    ushort_t* RE      = (ushort_t*)alloc((size_t)NC * 384 * 2);
    ushort_t* PF      = (ushort_t*)alloc((size_t)NF * 256 * 2);
    ushort_t* QF      = (ushort_t*)alloc((size_t)NF * 256 * 2);
    ushort_t* UfS     = (ushort_t*)alloc((size_t)NF * 128 * 2);
    ushort_t* Uf2     = (ushort_t*)alloc((size_t)NF * 128 * 2);
    ushort_t* aggS    = (ushort_t*)alloc((size_t)NF * 128 * 2);
    ushort_t* agg2    = (ushort_t*)alloc((size_t)NF * 128 * 2);
    ushort_t* agg1b   = (ushort_t*)alloc((size_t)NC * 64 * 2);
    ushort_t* xb      = (ushort_t*)alloc((size_t)NC * 128 * 2);
    ushort_t* WfA     = (ushort_t*)alloc(65536 * 2);
    ushort_t* WfE     = (ushort_t*)alloc(24576 * 2);
    ushort_t* WfSn    = (ushort_t*)alloc(16384 * 2);
    ushort_t* Wf1n    = (ushort_t*)alloc(12288 * 2);
    ushort_t* Wf2n    = (ushort_t*)alloc(16384 * 2);
    int*   cntF  = (int*)alloc((size_t)NF * sizeof(int));
    int*   srtF  = (int*)alloc((size_t)NF * CAPF * sizeof(int));
    int*   cntC  = (int*)alloc((size_t)NC * sizeof(int));
    int*   srtC  = (int*)alloc((size_t)NC * CAPC * sizeof(int));
    int*   cntG  = (int*)alloc((size_t)NCELL * sizeof(int));
    float4* grecs = (float4*)alloc((size_t)NCELL * CAPG * sizeof(float4));
    float* stats = (float*)alloc(256 * sizeof(float));
    float* outp = (float*)d_out;

    // 1. prep (converts + weight frags + zero counters/stats)
    constexpr int PREP_TOTAL = NC * 128 + 65536 + 24576 + 16384 + 12288 + 16384
                             + NF + NC + NCELL + 256;
    prep_kernel<<<(PREP_TOTAL + 255) / 256, 256, 0, stream>>>(
        x, xb, WeS, WnS, We1, We2, Wn2, Wn1,
        WfA, WfE, WfSn, Wf1n, Wf2n, cntF, cntC, cntG, stats);

    // 2. direct scatter into fixed-stride buckets
    constexpr int SORT_ITEMS = EF + EC + NC;
    scatter_kernel<<<(SORT_ITEMS + 255) / 256, 256, 0, stream>>>(
        ei_f, ei_c, pos_c, cntF, srtF, cntC, srtC, cntG, grecs);

    // 3. RA GEMM (bf16 out) + kNN
    gemmA_knn_kernel<<<768, 256, 0, stream>>>(
        xb, WfA, RA, pos_f, grecs, cntG, meta);

    // 4. coarse aggregation (mpl1)
    agg1_kernel<<<NC / 4, 256, 0, stream>>>(RA, cntC, srtC, be1, agg1b);

    // 5. node1 + gemmE -> RE
    nodeD_kernel<<<NC / 64, 256, 0, stream>>>(xb, agg1b, Wf1n, bn1, WfE, RE);

    // 6. pfBoth: interpolate P/Q/U from RA and RE (interleaved PF/QF)
    pfboth_kernel<<<NF / 4, 256, 0, stream>>>(
        RA, RE, meta, beS, be2, PF, QF, UfS, Uf2);

    // 7. aggBoth: single edge traversal, one gather per edge
    aggboth_kernel<<<NF / 4, 256, 0, stream>>>(
        PF, QF, cntF, srtF, aggS, agg2);

    // 8. nodeFinal: both node GEMMs + residual + BN stats
    nodeF_kernel<<<NF / 64, 256, 0, stream>>>(
        aggS, WfSn, bnS, UfS, agg2, Wf2n, bn2, Uf2, outp, stats);

    // 9. BN + SELU
    bn_kernel<<<NF * 128 / 256, 256, 0, stream>>>(outp, stats, gamma, beta, NF);
}